// Round 2
// baseline (740.743 us; speedup 1.0000x reference)
//
#include <hip/hip_runtime.h>
#include <hip/hip_bf16.h>
#include <stdint.h>

typedef __hip_bfloat16 bf16;
typedef __attribute__((ext_vector_type(8))) short bf16x8v;   // 8 bf16 = 4 VGPRs
typedef __attribute__((ext_vector_type(4))) float f32x4v;

#define B_   4
#define S_   8192
#define D_   1024
#define H_   16
#define DH_  64
#define M_TOT (B_ * S_)   // 32768

__device__ __forceinline__ float bf2f(bf16 x) { return __bfloat162float(x); }
__device__ __forceinline__ bf16  f2bf(float x) { return __float2bfloat16(x); }

__device__ __forceinline__ void storev(float* p, float v) { *p = v; }
__device__ __forceinline__ void storev(bf16* p, float v) { *p = f2bf(v); }

__device__ __forceinline__ void async_copy16(const void* g, void* l) {
  __builtin_amdgcn_global_load_lds(
      (const __attribute__((address_space(1))) unsigned int*)g,
      (__attribute__((address_space(3))) unsigned int*)l,
      16, 0, 0);
}

// ---------------------------------------------------------------------------
// fp32 -> bf16 bulk convert (4 elems/thread, vectorized)
// ---------------------------------------------------------------------------
__global__ __launch_bounds__(256) void f2bf_kernel(
    const float* __restrict__ in, bf16* __restrict__ out, int n4)
{
  const int i = blockIdx.x * 256 + threadIdx.x;
  if (i >= n4) return;
  const float4 v = ((const float4*)in)[i];
  union { bf16 h[4]; uint64_t u; } pk;
  pk.h[0] = f2bf(v.x); pk.h[1] = f2bf(v.y);
  pk.h[2] = f2bf(v.z); pk.h[3] = f2bf(v.w);
  ((uint64_t*)out)[i] = pk.u;
}

// ---------------------------------------------------------------------------
// GEMM: C[M,N] = A[M,K] @ BT[N,K]^T + bias[N] (+ addC[M,N]); bf16 in, fp32 acc
// 128x128 tile, BK=32, 256 threads = 4 waves (2x2), each wave 64x64 via 4x4 MFMAs
// ---------------------------------------------------------------------------
#define BM 128
#define BN 128
#define BK 32

template <typename OutT>
__global__ __launch_bounds__(256) void gemm_kernel(
    const bf16* __restrict__ A, const bf16* __restrict__ BT,
    const float* __restrict__ bias, const bf16* addC,
    OutT* __restrict__ C, int M, int N, int K, int perBatchB)
{
  __shared__ bf16 As[BM * BK];   // [m][k], 64B rows
  __shared__ bf16 Bs[BN * BK];   // [n][k]

  const int ntile = N / BN;
  const int tm = blockIdx.x / ntile, tn = blockIdx.x % ntile;
  const int m0 = tm * BM, n0 = tn * BN;
  const bf16* Bt = BT + (perBatchB ? (size_t)(m0 / S_) * (size_t)N * (size_t)K : 0);

  const int tid = threadIdx.x, wave = tid >> 6, lane = tid & 63;
  const int quad = lane >> 4, l16 = lane & 15;
  const int wm = (wave & 1) * 64, wn = (wave >> 1) * 64;

  // staging: wave w covers rows [w*32, w*32+32); lane -> (row = lane/4, 16B chunk)
  const int rowL = wave * 32 + (lane >> 2);
  const int kb = (lane & 3) * 16;
  const size_t sA = (size_t)K * 2;   // row stride bytes (A and BT both K-contig)
  const uint8_t* ga = (const uint8_t*)A  + (size_t)(m0 + rowL) * sA + kb;
  const uint8_t* gb = (const uint8_t*)Bt + (size_t)(n0 + rowL) * sA + kb;
  uint8_t* la = (uint8_t*)As + wave * 2048;   // wave-uniform LDS base
  uint8_t* lb = (uint8_t*)Bs + wave * 2048;

  f32x4v acc[4][4] = {};

  for (int k0 = 0; k0 < K; k0 += BK) {
    async_copy16(ga,            la);
    async_copy16(ga + 16 * sA,  la + 1024);
    async_copy16(gb,            lb);
    async_copy16(gb + 16 * sA,  lb + 1024);
    asm volatile("s_waitcnt vmcnt(0)" ::: "memory");
    __syncthreads();

    bf16x8v av[4], bv[4];
#pragma unroll
    for (int i = 0; i < 4; i++)
      av[i] = *(const bf16x8v*)(As + (wm + i * 16 + l16) * BK + quad * 8);
#pragma unroll
    for (int j = 0; j < 4; j++)
      bv[j] = *(const bf16x8v*)(Bs + (wn + j * 16 + l16) * BK + quad * 8);
#pragma unroll
    for (int i = 0; i < 4; i++)
#pragma unroll
      for (int j = 0; j < 4; j++)
        acc[i][j] = __builtin_amdgcn_mfma_f32_16x16x32_bf16(av[i], bv[j], acc[i][j], 0, 0, 0);
    __syncthreads();
    ga += BK * 2; gb += BK * 2;
  }

  // epilogue: C/D layout col=lane&15, row=quad*4+reg
#pragma unroll
  for (int i = 0; i < 4; i++) {
    const int row = m0 + wm + i * 16 + quad * 4;
#pragma unroll
    for (int j = 0; j < 4; j++) {
      const int col = n0 + wn + j * 16 + l16;
      const float bb = bias ? bias[col] : 0.f;
      f32x4v v = acc[i][j];
#pragma unroll
      for (int r = 0; r < 4; r++) {
        size_t idx = (size_t)(row + r) * N + col;
        float o = v[r] + bb;
        if (addC) o += bf2f(addC[idx]);
        storev(&C[idx], o);
      }
    }
  }
}

// ---------------------------------------------------------------------------
// Scores: raw[b*H+h][s] = sum_d X[b*S+s][d] * WaT[(b)][h][d]   (fp32 out)
// one wave = 16 rows, full K via MFMA; N=16 is exactly one tile col
// ---------------------------------------------------------------------------
__global__ __launch_bounds__(256) void score_kernel(
    const bf16* __restrict__ X, const bf16* __restrict__ WaT,
    float* __restrict__ scores, int perBatchW)
{
  const int tid = threadIdx.x, wave = tid >> 6, lane = tid & 63;
  const int quad = lane >> 4, l16 = lane & 15;
  const int row0 = blockIdx.x * 64 + wave * 16;
  const int b = row0 / S_;
  const bf16* W = WaT + (perBatchW ? (size_t)b * H_ * D_ : 0);
  const bf16* arow = X + (size_t)(row0 + l16) * D_;
  const bf16* brow = W + (size_t)l16 * D_;
  f32x4v acc = {};
  for (int k0 = 0; k0 < D_; k0 += 32) {
    bf16x8v av = *(const bf16x8v*)(arow + k0 + quad * 8);
    bf16x8v bv = *(const bf16x8v*)(brow + k0 + quad * 8);
    acc = __builtin_amdgcn_mfma_f32_16x16x32_bf16(av, bv, acc, 0, 0, 0);
  }
  const int srel = (row0 % S_) + quad * 4;
  float* orow = scores + ((size_t)b * H_ + l16) * S_ + srel;
#pragma unroll
  for (int r = 0; r < 4; r++) orow[r] = acc[r];
}

// softmax stats per (b,h): M = max_s(raw*scale + mask), sum = sum exp(.-M)
// (bqa/bka are constant per row -> softmax-invariant, dropped)
__global__ __launch_bounds__(256) void stats_kernel(
    const float* __restrict__ sc, const float* __restrict__ mask,
    float scale, float* __restrict__ stats)
{
  const int bh = blockIdx.x, b = bh >> 4, tid = threadIdx.x;
  const float* row = sc + (size_t)bh * S_;
  const float* mrow = mask + (size_t)b * S_;
  __shared__ float red[256];
  float m = -3.4e38f;
  for (int s = tid; s < S_; s += 256) m = fmaxf(m, row[s] * scale + mrow[s]);
  red[tid] = m; __syncthreads();
  for (int o = 128; o > 0; o >>= 1) { if (tid < o) red[tid] = fmaxf(red[tid], red[tid + o]); __syncthreads(); }
  const float M = red[0]; __syncthreads();
  float sum = 0.f;
  for (int s = tid; s < S_; s += 256) sum += expf(row[s] * scale + mrow[s] - M);
  red[tid] = sum; __syncthreads();
  for (int o = 128; o > 0; o >>= 1) { if (tid < o) red[tid] += red[tid + o]; __syncthreads(); }
  if (tid == 0) { stats[bh * 2] = M; stats[bh * 2 + 1] = red[0]; }
}

// pooled[b, h*64+dh] += sum_s softmax_w(s) * X[b*S+s][h*64+dh]  (fp32 atomics)
__global__ __launch_bounds__(256) void pool_kernel(
    const float* __restrict__ sc, const float* __restrict__ mask,
    const float* __restrict__ stats, const bf16* __restrict__ X,
    float* __restrict__ pooled, float scale)
{
  const int bh = blockIdx.x, chunk = blockIdx.y;
  const int b = bh >> 4, h = bh & 15;
  const int dh = threadIdx.x & 63, sr = threadIdx.x >> 6;
  const float M = stats[bh * 2], inv = 1.f / stats[bh * 2 + 1];
  const float* row = sc + (size_t)bh * S_;
  const float* mrow = mask + (size_t)b * S_;
  float acc = 0.f;
  const int s0 = chunk * 256;
  for (int s = s0 + sr; s < s0 + 256; s += 4) {
    float w = expf(row[s] * scale + mrow[s] - M) * inv;
    acc += w * bf2f(X[((size_t)b * S_ + s) * D_ + h * DH_ + dh]);
  }
  __shared__ float red[256];
  red[threadIdx.x] = acc; __syncthreads();
  if (sr == 0)
    atomicAdd(&pooled[b * D_ + h * DH_ + dh],
              red[dh] + red[64 + dh] + red[128 + dh] + red[192 + dh]);
}

// WaT[b][h][d] = Wa[d][h] * (pq ? pq[b][d] : 1)   (fp32 weights in, bf16 out)
__global__ __launch_bounds__(256) void prep_wa_kernel(
    const float* __restrict__ Wa, const float* __restrict__ pq,
    bf16* __restrict__ out, int nb)
{
  const int idx = blockIdx.x * 256 + threadIdx.x;
  if (idx >= nb * H_ * D_) return;
  const int d = idx & (D_ - 1);
  const int h = (idx >> 10) & 15;
  const int b = idx >> 14;
  float v = Wa[d * H_ + h];
  if (pq) v *= pq[b * D_ + d];
  out[idx] = f2bf(v);
}

// WT[n][k] = W[k][n]   (fp32 in, bf16 out)
__global__ __launch_bounds__(1024) void transpose_kernel(
    const float* __restrict__ W, bf16* __restrict__ WT)
{
  __shared__ float t[32][33];
  const int tx = threadIdx.x, ty = threadIdx.y;
  const int bx = blockIdx.x, by = blockIdx.y;
  t[ty][tx] = W[(size_t)(by * 32 + ty) * D_ + bx * 32 + tx];
  __syncthreads();
  WT[(size_t)(bx * 32 + ty) * D_ + by * 32 + tx] = f2bf(t[tx][ty]);
}

// out[b][n][k] = Wt[k][n] * pq[b][k] * pk[b][k]   (fp32 in, bf16 out)
__global__ __launch_bounds__(1024) void transpose_scale_kernel(
    const float* __restrict__ W, const float* __restrict__ pq,
    const float* __restrict__ pk, bf16* __restrict__ out)
{
  __shared__ float t[32][33];
  const int tx = threadIdx.x, ty = threadIdx.y;
  const int bx = blockIdx.x, by = blockIdx.y, b = blockIdx.z;
  t[ty][tx] = W[(size_t)(by * 32 + ty) * D_ + bx * 32 + tx];
  __syncthreads();
  const int n = bx * 32 + ty, k = by * 32 + tx;
  const float s = pq[b * D_ + k] * pk[b * D_ + k];
  out[(size_t)b * D_ * D_ + (size_t)n * D_ + k] = f2bf(t[tx][ty] * s);
}

extern "C" void kernel_launch(void* const* d_in, const int* in_sizes, int n_in,
                              void* d_out, int out_size, void* d_ws, size_t ws_size,
                              hipStream_t stream)
{
  const float* hs   = (const float*)d_in[0];
  const float* mask = (const float*)d_in[1];
  const float* Wq   = (const float*)d_in[2];
  const float* bq   = (const float*)d_in[3];
  const float* Wqa  = (const float*)d_in[4];
  const float* Wk   = (const float*)d_in[6];
  const float* bk   = (const float*)d_in[7];
  const float* Wka  = (const float*)d_in[8];
  const float* Wt   = (const float*)d_in[10];
  const float* bt   = (const float*)d_in[11];
  float* out = (float*)d_out;

  uint8_t* w = (uint8_t*)d_ws;
  bf16*  hs_bf     = (bf16*)(w + 0);           // 67108864
  bf16*  mixed_q   = (bf16*)(w + 67108864);    // 67108864
  bf16*  mixed_k   = (bf16*)(w + 134217728);   // 67108864
  bf16*  WqT       = (bf16*)(w + 201326592);   // 2097152
  bf16*  WkT       = (bf16*)(w + 203423744);   // 2097152
  bf16*  WtTs      = (bf16*)(w + 205520896);   // 8388608 (4 batches)
  bf16*  WaqT      = (bf16*)(w + 213909504);   // 32768
  bf16*  WakTs     = (bf16*)(w + 213942272);   // 131072
  float* scores_q  = (float*)(w + 214073344);  // 2097152
  float* scores_qk = (float*)(w + 216170496);  // 2097152
  float* stats_q   = (float*)(w + 218267648);  // 512
  float* stats_qk  = (float*)(w + 218268160);  // 512
  float* pq_raw    = (float*)(w + 218268672);  // 16384
  float* pk_raw    = (float*)(w + 218285056);  // 16384  (end ~218.3 MB)

  const float scale = 0.125f;   // 1/sqrt(DH)
  dim3 tblk(32, 32);

  // hidden_states fp32 -> bf16
  f2bf_kernel<<<(M_TOT * D_ / 4 + 255) / 256, 256, 0, stream>>>(hs, hs_bf, M_TOT * D_ / 4);

  // weight transposes for GEMM B-operand ([N][K], K contiguous), fp32 -> bf16
  transpose_kernel<<<dim3(32, 32), tblk, 0, stream>>>(Wq, WqT);
  transpose_kernel<<<dim3(32, 32), tblk, 0, stream>>>(Wk, WkT);

  // mixed_q / mixed_k (bf16 outputs for downstream MFMA use)
  gemm_kernel<bf16><<<2048, 256, 0, stream>>>(hs_bf, WqT, bq, nullptr, mixed_q, M_TOT, D_, D_, 0);
  gemm_kernel<bf16><<<2048, 256, 0, stream>>>(hs_bf, WkT, bk, nullptr, mixed_k, M_TOT, D_, D_, 0);

  // zero pooled accumulators (pq_raw|pk_raw contiguous)
  hipMemsetAsync(pq_raw, 0, 2 * D_ * B_ * sizeof(float), stream);

  // q attention pooling
  prep_wa_kernel<<<64, 256, 0, stream>>>(Wqa, nullptr, WaqT, 1);
  score_kernel<<<512, 256, 0, stream>>>(mixed_q, WaqT, scores_q, 0);
  stats_kernel<<<64, 256, 0, stream>>>(scores_q, mask, scale, stats_q);
  pool_kernel<<<dim3(64, 32), 256, 0, stream>>>(scores_q, mask, stats_q, mixed_q, pq_raw, scale);

  // qk attention pooling (pooled_q folded into Wka; mixed_qk never materialized)
  prep_wa_kernel<<<256, 256, 0, stream>>>(Wka, pq_raw, WakTs, 4);
  score_kernel<<<512, 256, 0, stream>>>(mixed_k, WakTs, scores_qk, 1);
  stats_kernel<<<64, 256, 0, stream>>>(scores_qk, mask, scale, stats_qk);
  pool_kernel<<<dim3(64, 32), 256, 0, stream>>>(scores_qk, mask, stats_qk, mixed_k, pk_raw, scale);

  // Wt scaled per batch by pooled_k = pq*pk_raw, transposed to [N][K]
  transpose_scale_kernel<<<dim3(32, 32, 4), tblk, 0, stream>>>(Wt, pq_raw, pk_raw, WtTs);

  // out = (mixed_q ⊙ pooled_k) @ Wt + bt + mixed_q   (fp32 output)
  gemm_kernel<float><<<2048, 256, 0, stream>>>(mixed_q, WtTs, bt, mixed_q, out, M_TOT, D_, D_, 1);
}

// Round 3
// 705.596 us; speedup vs baseline: 1.0498x; 1.0498x over previous
//
#include <hip/hip_runtime.h>
#include <hip/hip_bf16.h>
#include <stdint.h>

typedef __hip_bfloat16 bf16;
typedef __attribute__((ext_vector_type(8))) short bf16x8v;   // 8 bf16 = 4 VGPRs
typedef __attribute__((ext_vector_type(4))) float f32x4v;

#define B_   4
#define S_   8192
#define D_   1024
#define H_   16
#define DH_  64
#define M_TOT (B_ * S_)   // 32768

__device__ __forceinline__ float bf2f(bf16 x) { return __bfloat162float(x); }
__device__ __forceinline__ bf16  f2bf(float x) { return __float2bfloat16(x); }

__device__ __forceinline__ void storev(float* p, float v) { *p = v; }
__device__ __forceinline__ void storev(bf16* p, float v) { *p = f2bf(v); }

__device__ __forceinline__ void async_copy16(const void* g, void* l) {
  __builtin_amdgcn_global_load_lds(
      (const __attribute__((address_space(1))) unsigned int*)g,
      (__attribute__((address_space(3))) unsigned int*)l,
      16, 0, 0);
}

// ---------------------------------------------------------------------------
// fp32 -> bf16 bulk convert (4 elems/thread, vectorized)
// ---------------------------------------------------------------------------
__global__ __launch_bounds__(256) void f2bf_kernel(
    const float* __restrict__ in, bf16* __restrict__ out, int n4)
{
  const int i = blockIdx.x * 256 + threadIdx.x;
  if (i >= n4) return;
  const float4 v = ((const float4*)in)[i];
  union { bf16 h[4]; uint64_t u; } pk;
  pk.h[0] = f2bf(v.x); pk.h[1] = f2bf(v.y);
  pk.h[2] = f2bf(v.z); pk.h[3] = f2bf(v.w);
  ((uint64_t*)out)[i] = pk.u;
}

// ---------------------------------------------------------------------------
// GEMM: C[M,Ncols] = A[M,K](lda) @ BT[Ncols,K]^T + bias(col) (+ addC(ldadd))
// bf16 in, fp32 acc. 128x128 tile, BK=32, 4 waves, 64x64/wave via 16x16x32 MFMA.
// XCD-aware swizzle: blocks sharing an A-slab land on the same XCD (bid&7).
// ---------------------------------------------------------------------------
#define BM 128
#define BN 128
#define BK 32

template <typename OutT>
__global__ __launch_bounds__(256) void gemm_kernel(
    const bf16* __restrict__ A, int lda, const bf16* __restrict__ BT,
    const float* __restrict__ bias0, const float* __restrict__ bias1,
    const bf16* addC, int ldadd,
    OutT* __restrict__ C, int ldc, int M, int Ncols, int K, int perBatchB)
{
  __shared__ bf16 As[BM * BK];   // [m][k], 64B rows
  __shared__ bf16 Bs[BN * BK];   // [n][k]

  const int ntile = Ncols / BN;
  const int mtiles = M / BM;
  // XCD swizzle: same-XCD consecutive blocks share tm (A-slab L2 reuse)
  const int xcd = blockIdx.x & 7;
  const int local = blockIdx.x >> 3;
  const int tn = local % ntile;
  const int tm = xcd * (mtiles >> 3) + local / ntile;
  const int m0 = tm * BM, n0 = tn * BN;
  const bf16* Bt = BT + (perBatchB ? (size_t)(m0 / S_) * (size_t)Ncols * (size_t)K : 0);

  const int tid = threadIdx.x, wave = tid >> 6, lane = tid & 63;
  const int quad = lane >> 4, l16 = lane & 15;
  const int wm = (wave & 1) * 64, wn = (wave >> 1) * 64;

  // staging: wave w covers rows [w*32, w*32+32); lane -> (row = lane/4, 16B chunk)
  const int rowL = wave * 32 + (lane >> 2);
  const int kb = (lane & 3) * 16;
  const size_t sA = (size_t)lda * 2;   // A row stride bytes
  const size_t sB = (size_t)K * 2;     // BT row stride bytes
  const uint8_t* ga = (const uint8_t*)A  + (size_t)(m0 + rowL) * sA + kb;
  const uint8_t* gb = (const uint8_t*)Bt + (size_t)(n0 + rowL) * sB + kb;
  uint8_t* la = (uint8_t*)As + wave * 2048;   // wave-uniform LDS base
  uint8_t* lb = (uint8_t*)Bs + wave * 2048;

  f32x4v acc[4][4] = {};

  for (int k0 = 0; k0 < K; k0 += BK) {
    async_copy16(ga,            la);
    async_copy16(ga + 16 * sA,  la + 1024);
    async_copy16(gb,            lb);
    async_copy16(gb + 16 * sB,  lb + 1024);
    asm volatile("s_waitcnt vmcnt(0)" ::: "memory");
    __syncthreads();

    bf16x8v av[4], bv[4];
#pragma unroll
    for (int i = 0; i < 4; i++)
      av[i] = *(const bf16x8v*)(As + (wm + i * 16 + l16) * BK + quad * 8);
#pragma unroll
    for (int j = 0; j < 4; j++)
      bv[j] = *(const bf16x8v*)(Bs + (wn + j * 16 + l16) * BK + quad * 8);
#pragma unroll
    for (int i = 0; i < 4; i++)
#pragma unroll
      for (int j = 0; j < 4; j++)
        acc[i][j] = __builtin_amdgcn_mfma_f32_16x16x32_bf16(av[i], bv[j], acc[i][j], 0, 0, 0);
    __syncthreads();
    ga += BK * 2; gb += BK * 2;
  }

  // epilogue: C/D layout col=lane&15, row=quad*4+reg
#pragma unroll
  for (int i = 0; i < 4; i++) {
    const int row = m0 + wm + i * 16 + quad * 4;
#pragma unroll
    for (int j = 0; j < 4; j++) {
      const int col = n0 + wn + j * 16 + l16;
      const float bb = (col < 1024) ? (bias0 ? bias0[col] : 0.f)
                                    : (bias1 ? bias1[col - 1024] : 0.f);
      f32x4v v = acc[i][j];
#pragma unroll
      for (int r = 0; r < 4; r++) {
        float o = v[r] + bb;
        if (addC) o += bf2f(addC[(size_t)(row + r) * ldadd + col]);
        storev(&C[(size_t)(row + r) * ldc + col], o);
      }
    }
  }
}

// ---------------------------------------------------------------------------
// Scores: raw[b*H+h][s] = sum_d X[b*S+s][d] * WaT[(b)][h][d]   (fp32 out)
// one wave = 16 rows, full K via MFMA; N=16 is exactly one tile col
// ---------------------------------------------------------------------------
__global__ __launch_bounds__(256) void score_kernel(
    const bf16* __restrict__ X, int ldx, const bf16* __restrict__ WaT,
    float* __restrict__ scores, int perBatchW)
{
  const int tid = threadIdx.x, wave = tid >> 6, lane = tid & 63;
  const int quad = lane >> 4, l16 = lane & 15;
  const int row0 = blockIdx.x * 64 + wave * 16;
  const int b = row0 / S_;
  const bf16* W = WaT + (perBatchW ? (size_t)b * H_ * D_ : 0);
  const bf16* arow = X + (size_t)(row0 + l16) * ldx;
  const bf16* brow = W + (size_t)l16 * D_;
  f32x4v acc = {};
  for (int k0 = 0; k0 < D_; k0 += 32) {
    bf16x8v av = *(const bf16x8v*)(arow + k0 + quad * 8);
    bf16x8v bv = *(const bf16x8v*)(brow + k0 + quad * 8);
    acc = __builtin_amdgcn_mfma_f32_16x16x32_bf16(av, bv, acc, 0, 0, 0);
  }
  const int srel = (row0 % S_) + quad * 4;
  float* orow = scores + ((size_t)b * H_ + l16) * S_ + srel;
#pragma unroll
  for (int r = 0; r < 4; r++) orow[r] = acc[r];
}

// softmax stats per (b,h): M = max_s(raw*scale + mask), sum = sum exp(.-M)
// (bqa/bka are constant per row -> softmax-invariant, dropped)
__global__ __launch_bounds__(256) void stats_kernel(
    const float* __restrict__ sc, const float* __restrict__ mask,
    float scale, float* __restrict__ stats)
{
  const int bh = blockIdx.x, b = bh >> 4, tid = threadIdx.x;
  const float* row = sc + (size_t)bh * S_;
  const float* mrow = mask + (size_t)b * S_;
  __shared__ float red[256];
  float m = -3.4e38f;
  for (int s = tid; s < S_; s += 256) m = fmaxf(m, row[s] * scale + mrow[s]);
  red[tid] = m; __syncthreads();
  for (int o = 128; o > 0; o >>= 1) { if (tid < o) red[tid] = fmaxf(red[tid], red[tid + o]); __syncthreads(); }
  const float M = red[0]; __syncthreads();
  float sum = 0.f;
  for (int s = tid; s < S_; s += 256) sum += expf(row[s] * scale + mrow[s] - M);
  red[tid] = sum; __syncthreads();
  for (int o = 128; o > 0; o >>= 1) { if (tid < o) red[tid] += red[tid + o]; __syncthreads(); }
  if (tid == 0) { stats[bh * 2] = M; stats[bh * 2 + 1] = red[0]; }
}

// pooled[b, h*64+dh] += sum_s softmax_w(s) * X[(b*S+s)*ldx + h*64+dh]  (fp32 atomics)
__global__ __launch_bounds__(256) void pool_kernel(
    const float* __restrict__ sc, const float* __restrict__ mask,
    const float* __restrict__ stats, const bf16* __restrict__ X, int ldx,
    float* __restrict__ pooled, float scale)
{
  const int bh = blockIdx.x, chunk = blockIdx.y;
  const int b = bh >> 4, h = bh & 15;
  const int dh = threadIdx.x & 63, sr = threadIdx.x >> 6;
  const float M = stats[bh * 2], inv = 1.f / stats[bh * 2 + 1];
  const float* row = sc + (size_t)bh * S_;
  const float* mrow = mask + (size_t)b * S_;
  float acc = 0.f;
  const int s0 = chunk * 256;
  for (int s = s0 + sr; s < s0 + 256; s += 4) {
    float w = expf(row[s] * scale + mrow[s] - M) * inv;
    acc += w * bf2f(X[((size_t)b * S_ + s) * ldx + h * DH_ + dh]);
  }
  __shared__ float red[256];
  red[threadIdx.x] = acc; __syncthreads();
  if (sr == 0)
    atomicAdd(&pooled[b * D_ + h * DH_ + dh],
              red[dh] + red[64 + dh] + red[128 + dh] + red[192 + dh]);
}

// WaT[b][h][d] = Wa[d][h] * (pq ? pq[b][d] : 1)   (fp32 weights in, bf16 out)
__global__ __launch_bounds__(256) void prep_wa_kernel(
    const float* __restrict__ Wa, const float* __restrict__ pq,
    bf16* __restrict__ out, int nb)
{
  const int idx = blockIdx.x * 256 + threadIdx.x;
  if (idx >= nb * H_ * D_) return;
  const int d = idx & (D_ - 1);
  const int h = (idx >> 10) & 15;
  const int b = idx >> 14;
  float v = Wa[d * H_ + h];
  if (pq) v *= pq[b * D_ + d];
  out[idx] = f2bf(v);
}

// WT[n][k] = W[k][n]   (fp32 in, bf16 out)
__global__ __launch_bounds__(1024) void transpose_kernel(
    const float* __restrict__ W, bf16* __restrict__ WT)
{
  __shared__ float t[32][33];
  const int tx = threadIdx.x, ty = threadIdx.y;
  const int bx = blockIdx.x, by = blockIdx.y;
  t[ty][tx] = W[(size_t)(by * 32 + ty) * D_ + bx * 32 + tx];
  __syncthreads();
  WT[(size_t)(bx * 32 + ty) * D_ + by * 32 + tx] = f2bf(t[tx][ty]);
}

// out[b][n][k] = Wt[k][n] * pq[b][k] * pk[b][k]   (fp32 in, bf16 out)
__global__ __launch_bounds__(1024) void transpose_scale_kernel(
    const float* __restrict__ W, const float* __restrict__ pq,
    const float* __restrict__ pk, bf16* __restrict__ out)
{
  __shared__ float t[32][33];
  const int tx = threadIdx.x, ty = threadIdx.y;
  const int bx = blockIdx.x, by = blockIdx.y, b = blockIdx.z;
  t[ty][tx] = W[(size_t)(by * 32 + ty) * D_ + bx * 32 + tx];
  __syncthreads();
  const int n = bx * 32 + ty, k = by * 32 + tx;
  const float s = pq[b * D_ + k] * pk[b * D_ + k];
  out[(size_t)b * D_ * D_ + (size_t)n * D_ + k] = f2bf(t[tx][ty] * s);
}

extern "C" void kernel_launch(void* const* d_in, const int* in_sizes, int n_in,
                              void* d_out, int out_size, void* d_ws, size_t ws_size,
                              hipStream_t stream)
{
  const float* hs   = (const float*)d_in[0];
  const float* mask = (const float*)d_in[1];
  const float* Wq   = (const float*)d_in[2];
  const float* bq   = (const float*)d_in[3];
  const float* Wqa  = (const float*)d_in[4];
  const float* Wk   = (const float*)d_in[6];
  const float* bk   = (const float*)d_in[7];
  const float* Wka  = (const float*)d_in[8];
  const float* Wt   = (const float*)d_in[10];
  const float* bt   = (const float*)d_in[11];
  float* out = (float*)d_out;

  uint8_t* w = (uint8_t*)d_ws;
  bf16*  hs_bf     = (bf16*)(w + 0);           // 67108864
  bf16*  mixed_qk  = (bf16*)(w + 67108864);    // [32768,2048] bf16 = 134217728
  bf16*  WqkT      = (bf16*)(w + 201326592);   // [2048,1024] bf16 = 4194304
  bf16*  WtTs      = (bf16*)(w + 205520896);   // 8388608 (4 batches)
  bf16*  WaqT      = (bf16*)(w + 213909504);   // 32768
  bf16*  WakTs     = (bf16*)(w + 213942272);   // 131072
  float* scores_q  = (float*)(w + 214073344);  // 2097152
  float* scores_qk = (float*)(w + 216170496);  // 2097152
  float* stats_q   = (float*)(w + 218267648);  // 512
  float* stats_qk  = (float*)(w + 218268160);  // 512
  float* pq_raw    = (float*)(w + 218268672);  // 16384
  float* pk_raw    = (float*)(w + 218285056);  // 16384  (end ~218.3 MB)

  const bf16* mixed_q = mixed_qk;           // cols 0..1023
  const bf16* mixed_k = mixed_qk + 1024;    // cols 1024..2047
  const int LDQK = 2048;

  const float scale = 0.125f;   // 1/sqrt(DH)
  dim3 tblk(32, 32);

  // hidden_states fp32 -> bf16
  f2bf_kernel<<<(M_TOT * D_ / 4 + 255) / 256, 256, 0, stream>>>(hs, hs_bf, M_TOT * D_ / 4);

  // weight transposes into stacked [WqT;WkT] ([2048][1024], K contiguous)
  transpose_kernel<<<dim3(32, 32), tblk, 0, stream>>>(Wq, WqkT);
  transpose_kernel<<<dim3(32, 32), tblk, 0, stream>>>(Wk, WqkT + 1024 * 1024);

  // fused mixed_q|mixed_k GEMM: [32768,1024] @ [1024,2048] -> [32768,2048]
  gemm_kernel<bf16><<<4096, 256, 0, stream>>>(
      hs_bf, 1024, WqkT, bq, bk, nullptr, 0, mixed_qk, LDQK, M_TOT, 2048, D_, 0);

  // zero pooled accumulators (pq_raw|pk_raw contiguous)
  hipMemsetAsync(pq_raw, 0, 2 * D_ * B_ * sizeof(float), stream);

  // q attention pooling
  prep_wa_kernel<<<64, 256, 0, stream>>>(Wqa, nullptr, WaqT, 1);
  score_kernel<<<512, 256, 0, stream>>>(mixed_q, LDQK, WaqT, scores_q, 0);
  stats_kernel<<<64, 256, 0, stream>>>(scores_q, mask, scale, stats_q);
  pool_kernel<<<dim3(64, 32), 256, 0, stream>>>(scores_q, mask, stats_q, mixed_q, LDQK, pq_raw, scale);

  // qk attention pooling (pooled_q folded into Wka; mixed_qk never materialized)
  prep_wa_kernel<<<256, 256, 0, stream>>>(Wka, pq_raw, WakTs, 4);
  score_kernel<<<512, 256, 0, stream>>>(mixed_k, LDQK, WakTs, scores_qk, 1);
  stats_kernel<<<64, 256, 0, stream>>>(scores_qk, mask, scale, stats_qk);
  pool_kernel<<<dim3(64, 32), 256, 0, stream>>>(scores_qk, mask, stats_qk, mixed_k, LDQK, pk_raw, scale);

  // Wt scaled per batch by pooled_k = pq*pk_raw, transposed to [N][K]
  transpose_scale_kernel<<<dim3(32, 32, 4), tblk, 0, stream>>>(Wt, pq_raw, pk_raw, WtTs);

  // out = (mixed_q ⊙ pooled_k) @ Wt + bt + mixed_q   (fp32 output)
  gemm_kernel<float><<<2048, 256, 0, stream>>>(
      mixed_q, LDQK, WtTs, bt, nullptr, mixed_q, LDQK, out, D_, M_TOT, D_, D_, 1);
}